// Round 2
// 428.853 us; speedup vs baseline: 1.0007x; 1.0007x over previous
//
#include <hip/hip_runtime.h>

// Z gate with DIM=2, S=1, INDEX=(0,5,10), L=14  =>  phase = (-1)^(parity of bits 13,8,3 of n)
// out[0] = sign(n) * x_real, out[1] = sign(n) * x_imag, each N*B floats.
// Flat element index e = n*B + b, B=2048 => sign bits of e at 14, 19, 24.
// float4 index i = e>>2 => sign bits of i at 12, 17, 22.
//
// Pure streaming kernel. Irreducible traffic = 536.9 MB (268.4 read + 268.4 write).
// Strategy: grid-stride with 2048 resident blocks (256 CU x 8), x4 unroll for MLP,
// nontemporal loads/stores (touch-once data, input stream > 256 MiB L3),
// integer XOR sign flip.
//
// NOTE: __builtin_nontemporal_* requires a clang vector type, not HIP_vector_type
// (uint4 is a class). Use ext_vector_type(4) of unsigned int — identical 16 B layout.

#define NB_TOTAL (16384LL * 2048LL)     // N*B = 33,554,432 elements per array
#define NVEC     ((int)(NB_TOTAL / 4))  // 8,388,608 16B-vectors per array

typedef unsigned int u32x4 __attribute__((ext_vector_type(4)));

__global__ __launch_bounds__(256) void z_phase_kernel(
    const u32x4* __restrict__ xr,
    const u32x4* __restrict__ xi,
    u32x4* __restrict__ outr,
    u32x4* __restrict__ outi)
{
    const int nthreads = gridDim.x * blockDim.x;            // 524,288
    int i = blockIdx.x * blockDim.x + threadIdx.x;

    // NVEC / nthreads = 16 iterations exactly; unroll 4 => 4 load-pairs in flight
    #pragma unroll 4
    for (; i < NVEC; i += nthreads) {
        unsigned int u = (unsigned int)i;
        unsigned int flip = (((u >> 12) ^ (u >> 17) ^ (u >> 22)) & 1u) << 31;

        u32x4 r = __builtin_nontemporal_load(&xr[i]);
        u32x4 m = __builtin_nontemporal_load(&xi[i]);

        r ^= flip;   // vector-splat XOR on all 4 lanes
        m ^= flip;

        __builtin_nontemporal_store(r, &outr[i]);
        __builtin_nontemporal_store(m, &outi[i]);
    }
}

extern "C" void kernel_launch(void* const* d_in, const int* in_sizes, int n_in,
                              void* d_out, int out_size, void* d_ws, size_t ws_size,
                              hipStream_t stream) {
    const u32x4* xr = (const u32x4*)d_in[0];
    const u32x4* xi = (const u32x4*)d_in[1];
    u32x4* outr = (u32x4*)d_out;                          // first N*B floats
    u32x4* outi = (u32x4*)((float*)d_out + NB_TOTAL);     // next N*B floats

    const int block = 256;
    const int grid = 2048;   // 256 CUs x 8 blocks/CU, grid-stride covers NVEC
    z_phase_kernel<<<grid, block, 0, stream>>>(xr, xi, outr, outi);
}